// Round 1
// baseline (2873.504 us; speedup 1.0000x reference)
//
#include <hip/hip_runtime.h>
#include <math.h>

#define VNUM 50000
#define OUTF 128
#define NEDGE 1600000
#define EPSF 1e-7f

// ---------------------------------------------------------------------------
// Phase 1: edge scatter. 32 threads per edge (4 cols each as float4),
// 8 edges per 256-thread block. HW float atomics (global_atomic_add_f32).
// Accumulator = first half of d_out (loc region), zeroed by memset before.
// ---------------------------------------------------------------------------
__global__ __launch_bounds__(256) void scatter_kernel(
    const int* __restrict__ sidx, const int* __restrict__ tidx,
    const float* __restrict__ enorm, const float* __restrict__ esgn,
    const float* __restrict__ vrepr, float* acc)
{
    const int tid  = threadIdx.x;
    const int sub  = tid >> 5;   // edge within block: 0..7
    const int lane = tid & 31;   // column group: 4 cols each
    const int e = blockIdx.x * 8 + sub;   // grid sized exactly: E/8 blocks

    const float w = esgn[e] * enorm[e];
    const int s = sidx[e];
    const int t = tidx[e];

    const float4 v = *reinterpret_cast<const float4*>(
        vrepr + (size_t)s * OUTF + lane * 4);

    float* dst = acc + (size_t)t * OUTF + lane * 4;
    unsafeAtomicAdd(dst + 0, v.x * w);
    unsafeAtomicAdd(dst + 1, v.y * w);
    unsafeAtomicAdd(dst + 2, v.z * w);
    unsafeAtomicAdd(dst + 3, v.w * w);
}

// ---------------------------------------------------------------------------
// Phase 2: dual 128x128 projection + bias (+ softplus for std head).
// Block = 256 threads handles 16 rows. ptr rows staged in LDS (8 KB).
// Thread t computes column (t&127) of head (t>>7) for all 16 rows.
// Reads acc rows then overwrites them (loc head) — block-local aliasing only.
// ---------------------------------------------------------------------------
__global__ __launch_bounds__(256) void gemm_kernel(
    const float* acc,
    const float* __restrict__ loc_w, const float* __restrict__ loc_b,
    const float* __restrict__ std_w, const float* __restrict__ std_b,
    float* out)
{
    __shared__ float tile[16][OUTF];   // 8 KB

    const int t    = threadIdx.x;
    const int row0 = blockIdx.x * 16;

    // Stage 16x128 = 2048 floats: each thread moves 2 float4s, coalesced.
    {
        const float4* src = reinterpret_cast<const float4*>(acc + (size_t)row0 * OUTF);
        float4* dst = reinterpret_cast<float4*>(&tile[0][0]);
        dst[t]       = src[t];
        dst[t + 256] = src[t + 256];
    }
    __syncthreads();

    const int is_std = t >> 7;     // 0 = loc head, 1 = std head
    const int c      = t & 127;    // output column

    const float* w = (is_std ? std_w : loc_w) + (size_t)c * OUTF;
    const float bias = is_std ? std_b[c] : loc_b[c];

    float accv[16];
#pragma unroll
    for (int r = 0; r < 16; ++r) accv[r] = 0.0f;

    for (int k = 0; k < OUTF; k += 4) {
        const float4 wv = *reinterpret_cast<const float4*>(w + k);
#pragma unroll
        for (int r = 0; r < 16; ++r) {
            const float4 pv = *reinterpret_cast<const float4*>(&tile[r][k]);
            float a = accv[r];
            a = fmaf(pv.x, wv.x, a);
            a = fmaf(pv.y, wv.y, a);
            a = fmaf(pv.z, wv.z, a);
            a = fmaf(pv.w, wv.w, a);
            accv[r] = a;
        }
    }

    float* dst_base = out + (is_std ? (size_t)VNUM * OUTF : (size_t)0);
#pragma unroll
    for (int r = 0; r < 16; ++r) {
        const float x = accv[r] + bias;
        float res;
        if (is_std) {
            // softplus(x) = max(x,0) + log1p(exp(-|x|)); numerically stable
            res = fmaxf(x, 0.0f) + log1pf(expf(-fabsf(x))) + EPSF;
        } else {
            res = x;
        }
        dst_base[(size_t)(row0 + r) * OUTF + c] = res;
    }
}

extern "C" void kernel_launch(void* const* d_in, const int* in_sizes, int n_in,
                              void* d_out, int out_size, void* d_ws, size_t ws_size,
                              hipStream_t stream) {
    const int*   sidx  = (const int*)  d_in[0];
    const int*   tidx  = (const int*)  d_in[1];
    const float* enorm = (const float*)d_in[2];
    const float* esgn  = (const float*)d_in[3];
    const float* vrepr = (const float*)d_in[4];
    const float* loc_w = (const float*)d_in[5];
    const float* loc_b = (const float*)d_in[6];
    const float* std_w = (const float*)d_in[7];
    const float* std_b = (const float*)d_in[8];

    float* out = (float*)d_out;
    float* acc = out;  // loc half of d_out doubles as the segment-sum buffer

    // zero the accumulator region (d_out is poisoned before every call)
    hipMemsetAsync(acc, 0, (size_t)VNUM * OUTF * sizeof(float), stream);

    // scatter: E/8 blocks of 256 (8 edges x 32 threads)
    scatter_kernel<<<NEDGE / 8, 256, 0, stream>>>(sidx, tidx, enorm, esgn, vrepr, acc);

    // projection: 50000/16 = 3125 blocks
    gemm_kernel<<<VNUM / 16, 256, 0, stream>>>(acc, loc_w, loc_b, std_w, std_b, out);
}

// Round 2
// 642.090 us; speedup vs baseline: 4.4752x; 4.4752x over previous
//
#include <hip/hip_runtime.h>
#include <math.h>

#define VNUM 50000
#define OUTF 128
#define NEDGE 1600000
#define EPSF 1e-7f

// ---------------------------------------------------------------------------
// Counting-sort edges by target vertex into CSR, then gather-based segment
// sum (no float atomics), then dual 128x128 projection.
//
// Scratch lives in the std half of d_out (dead until the final GEMM writes):
//   s_sorted : E ints     w_sorted : E floats
//   cnt      : VNUM ints  offs     : VNUM+1 ints   cursor : VNUM ints
//   total = 2E + 3*VNUM + 1 = 3,350,001 ints <= VNUM*OUTF = 6,400,000  OK
// ---------------------------------------------------------------------------

__global__ __launch_bounds__(256) void hist_kernel(
    const int* __restrict__ tidx, int* __restrict__ cnt)
{
    const int e = blockIdx.x * 256 + threadIdx.x;
    atomicAdd(&cnt[tidx[e]], 1);
}

// Single-block exclusive scan of 50000 counts -> offs[0..VNUM], cursor copy.
__global__ __launch_bounds__(256) void scan_kernel(
    const int* __restrict__ cnt, int* __restrict__ offs, int* __restrict__ cursor)
{
    __shared__ int tsum[256];
    __shared__ int tpre[256];
    const int tid = threadIdx.x;
    const int CH = (VNUM + 255) / 256;   // 196
    const int beg = tid * CH;
    const int end = (beg + CH < VNUM) ? beg + CH : VNUM;

    int s = 0;
    for (int i = beg; i < end; ++i) s += cnt[i];
    tsum[tid] = s;
    __syncthreads();
    if (tid == 0) {
        int run = 0;
        for (int i = 0; i < 256; ++i) { tpre[i] = run; run += tsum[i]; }
        offs[VNUM] = run;   // == NEDGE
    }
    __syncthreads();
    int run = tpre[tid];
    for (int i = beg; i < end; ++i) {
        offs[i] = run; cursor[i] = run;
        run += cnt[i];
    }
}

__global__ __launch_bounds__(256) void bucket_kernel(
    const int* __restrict__ sidx, const int* __restrict__ tidx,
    const float* __restrict__ enorm, const float* __restrict__ esgn,
    int* __restrict__ cursor, int* __restrict__ s_sorted, float* __restrict__ w_sorted)
{
    const int e = blockIdx.x * 256 + threadIdx.x;
    const int t = tidx[e];
    const int pos = atomicAdd(&cursor[t], 1);
    s_sorted[pos] = sidx[e];
    w_sorted[pos] = esgn[e] * enorm[e];
}

// One 128-thread group per vertex; thread = output column. Coalesced 512 B
// row gathers of vrepr (L2/LLC-resident), wave-uniform (s, w) broadcasts.
__global__ __launch_bounds__(256) void aggregate_kernel(
    const int* __restrict__ offs, const int* __restrict__ s_sorted,
    const float* __restrict__ w_sorted, const float* __restrict__ vrepr,
    float* __restrict__ acc)
{
    const int v = blockIdx.x * 2 + (threadIdx.x >> 7);
    const int j = threadIdx.x & 127;
    const int beg = offs[v];
    const int end = offs[v + 1];

    float a = 0.0f;
    int i = beg;
    for (; i + 1 < end; i += 2) {       // unroll 2: two gathers in flight
        const int   s0 = s_sorted[i],     s1 = s_sorted[i + 1];
        const float w0 = w_sorted[i],     w1 = w_sorted[i + 1];
        const float v0 = vrepr[(size_t)s0 * OUTF + j];
        const float v1 = vrepr[(size_t)s1 * OUTF + j];
        a = fmaf(v0, w0, a);
        a = fmaf(v1, w1, a);
    }
    if (i < end)
        a = fmaf(vrepr[(size_t)s_sorted[i] * OUTF + j], w_sorted[i], a);

    acc[(size_t)v * OUTF + j] = a;
}

// Dual 128x128 projection + bias (+ softplus for std head).
__global__ __launch_bounds__(256) void gemm_kernel(
    const float* acc,
    const float* __restrict__ loc_w, const float* __restrict__ loc_b,
    const float* __restrict__ std_w, const float* __restrict__ std_b,
    float* out)
{
    __shared__ float tile[16][OUTF];   // 8 KB

    const int t    = threadIdx.x;
    const int row0 = blockIdx.x * 16;

    {
        const float4* src = reinterpret_cast<const float4*>(acc + (size_t)row0 * OUTF);
        float4* dst = reinterpret_cast<float4*>(&tile[0][0]);
        dst[t]       = src[t];
        dst[t + 256] = src[t + 256];
    }
    __syncthreads();

    const int is_std = t >> 7;
    const int c      = t & 127;

    const float* w = (is_std ? std_w : loc_w) + (size_t)c * OUTF;
    const float bias = is_std ? std_b[c] : loc_b[c];

    float accv[16];
#pragma unroll
    for (int r = 0; r < 16; ++r) accv[r] = 0.0f;

    for (int k = 0; k < OUTF; k += 4) {
        const float4 wv = *reinterpret_cast<const float4*>(w + k);
#pragma unroll
        for (int r = 0; r < 16; ++r) {
            const float4 pv = *reinterpret_cast<const float4*>(&tile[r][k]);
            float a = accv[r];
            a = fmaf(pv.x, wv.x, a);
            a = fmaf(pv.y, wv.y, a);
            a = fmaf(pv.z, wv.z, a);
            a = fmaf(pv.w, wv.w, a);
            accv[r] = a;
        }
    }

    float* dst_base = out + (is_std ? (size_t)VNUM * OUTF : (size_t)0);
#pragma unroll
    for (int r = 0; r < 16; ++r) {
        const float x = accv[r] + bias;
        float res;
        if (is_std) {
            res = fmaxf(x, 0.0f) + log1pf(expf(-fabsf(x))) + EPSF;
        } else {
            res = x;
        }
        dst_base[(size_t)(row0 + r) * OUTF + c] = res;
    }
}

extern "C" void kernel_launch(void* const* d_in, const int* in_sizes, int n_in,
                              void* d_out, int out_size, void* d_ws, size_t ws_size,
                              hipStream_t stream) {
    const int*   sidx  = (const int*)  d_in[0];
    const int*   tidx  = (const int*)  d_in[1];
    const float* enorm = (const float*)d_in[2];
    const float* esgn  = (const float*)d_in[3];
    const float* vrepr = (const float*)d_in[4];
    const float* loc_w = (const float*)d_in[5];
    const float* loc_b = (const float*)d_in[6];
    const float* std_w = (const float*)d_in[7];
    const float* std_b = (const float*)d_in[8];

    float* out = (float*)d_out;
    float* acc = out;                                   // loc half = segment sums

    // scratch in the std half of d_out
    int*   base     = (int*)(out + (size_t)VNUM * OUTF);
    int*   s_sorted = base;
    float* w_sorted = (float*)(base + NEDGE);
    int*   cnt      = base + 2 * NEDGE;
    int*   offs     = base + 2 * NEDGE + VNUM;
    int*   cursor   = base + 2 * NEDGE + 2 * VNUM + 1;

    hipMemsetAsync(cnt, 0, VNUM * sizeof(int), stream);

    hist_kernel    <<<NEDGE / 256, 256, 0, stream>>>(tidx, cnt);
    scan_kernel    <<<1,           256, 0, stream>>>(cnt, offs, cursor);
    bucket_kernel  <<<NEDGE / 256, 256, 0, stream>>>(sidx, tidx, enorm, esgn,
                                                     cursor, s_sorted, w_sorted);
    aggregate_kernel<<<VNUM / 2,   256, 0, stream>>>(offs, s_sorted, w_sorted,
                                                     vrepr, acc);
    gemm_kernel    <<<VNUM / 16,   256, 0, stream>>>(acc, loc_w, loc_b,
                                                     std_w, std_b, out);
}

// Round 3
// 523.686 us; speedup vs baseline: 5.4871x; 1.2261x over previous
//
#include <hip/hip_runtime.h>
#include <math.h>

#define VNUM 50000
#define OUTF 128
#define NEDGE 1600000
#define EPSF 1e-7f

#define CONV_BLOCKS 6250   // 50000*128 / (256*4)
#define HIST_BLOCKS 6250   // 1600000 / 256

// ---------------------------------------------------------------------------
// bf16 helpers (self-contained, RNE)
// ---------------------------------------------------------------------------
__device__ __forceinline__ unsigned short f2bf(float f) {
    union { float f; unsigned int u; } c; c.f = f;
    unsigned int u = c.u;
    return (unsigned short)((u + 0x7FFFu + ((u >> 16) & 1u)) >> 16);
}
__device__ __forceinline__ float bf16_lo(unsigned int p) {
    union { unsigned int u; float f; } c; c.u = p << 16; return c.f;
}
__device__ __forceinline__ float bf16_hi(unsigned int p) {
    union { unsigned int u; float f; } c; c.u = p & 0xFFFF0000u; return c.f;
}

// ---------------------------------------------------------------------------
// prep: fused (a) vrepr f32 -> packed bf16x2, (b) histogram of tidx,
// (c) weight transpose into d_ws (only when ws available).
// ---------------------------------------------------------------------------
__global__ __launch_bounds__(256) void prep_kernel(
    const float* __restrict__ vrepr, unsigned int* __restrict__ vrepr16,
    const int* __restrict__ tidx, int* __restrict__ cnt,
    const float* __restrict__ loc_w, const float* __restrict__ std_w,
    float* wT)
{
    const int b = blockIdx.x, tid = threadIdx.x;
    if (b < CONV_BLOCKS) {
        const size_t base = (size_t)b * 1024 + tid * 4;
        const float4 v = *reinterpret_cast<const float4*>(vrepr + base);
        uint2 o;
        o.x = (unsigned)f2bf(v.x) | ((unsigned)f2bf(v.y) << 16);
        o.y = (unsigned)f2bf(v.z) | ((unsigned)f2bf(v.w) << 16);
        *reinterpret_cast<uint2*>(vrepr16 + base / 2) = o;
    } else if (b < CONV_BLOCKS + HIST_BLOCKS) {
        const int e = (b - CONV_BLOCKS) * 256 + tid;
        atomicAdd(&cnt[tidx[e]], 1);
    } else {
        // 128 transpose blocks: wT[h][k][c] = w_h[c][k]
        const int i = b - (CONV_BLOCKS + HIST_BLOCKS);  // 0..127
        const int h = i >> 6, kq = i & 63;
        const int k = kq * 2 + (tid >> 7);
        const int c = tid & 127;
        const float* w = h ? std_w : loc_w;
        wT[h * 16384 + k * 128 + c] = w[c * 128 + k];
    }
}

// ---------------------------------------------------------------------------
// scan: exclusive prefix over 50000 counts. 1024 threads, wave-shuffle scan.
// ---------------------------------------------------------------------------
__global__ __launch_bounds__(1024) void scan_kernel(
    const int* __restrict__ cnt, int* __restrict__ offs, int* __restrict__ cursor)
{
    __shared__ int wsum[16], wpre[16];
    const int tid = threadIdx.x;
    const int beg = tid * 49;        // 1024*49 = 50176 >= VNUM

    int s = 0;
#pragma unroll
    for (int i = 0; i < 49; ++i) {
        const int idx = beg + i;
        s += (idx < VNUM) ? cnt[idx] : 0;
    }
    const int lane = tid & 63, wave = tid >> 6;
    int v = s;
#pragma unroll
    for (int off = 1; off < 64; off <<= 1) {
        const int o = __shfl_up(v, off, 64);
        if (lane >= off) v += o;
    }
    if (lane == 63) wsum[wave] = v;
    __syncthreads();
    if (tid == 0) {
        int run = 0;
        for (int w2 = 0; w2 < 16; ++w2) { wpre[w2] = run; run += wsum[w2]; }
        offs[VNUM] = run;   // == NEDGE
    }
    __syncthreads();
    int run = wpre[wave] + (v - s);  // exclusive prefix for this thread
#pragma unroll
    for (int i = 0; i < 49; ++i) {
        const int idx = beg + i;
        if (idx < VNUM) {
            offs[idx] = run; cursor[idx] = run;
            run += cnt[idx];
        }
    }
}

// ---------------------------------------------------------------------------
// bucket: scatter packed (s<<16 | bf16(w)) into sorted position. One 4B
// write per edge.
// ---------------------------------------------------------------------------
__global__ __launch_bounds__(256) void bucket_kernel(
    const int* __restrict__ sidx, const int* __restrict__ tidx,
    const float* __restrict__ enorm, const float* __restrict__ esgn,
    int* __restrict__ cursor, unsigned int* __restrict__ pairs)
{
    const int e = blockIdx.x * 256 + threadIdx.x;
    const int t = tidx[e];
    const float w = esgn[e] * enorm[e];
    const int pos = atomicAdd(&cursor[t], 1);
    pairs[pos] = ((unsigned)sidx[e] << 16) | (unsigned)f2bf(w);
}

// ---------------------------------------------------------------------------
// aggregate: one wave per vertex, lane covers 2 columns. 256B coalesced
// bf16-row gathers, unroll-4 for MLP. Writes f32 acc (coalesced float2).
// ---------------------------------------------------------------------------
__global__ __launch_bounds__(256) void aggregate_kernel(
    const int* __restrict__ offs, const unsigned int* __restrict__ pairs,
    const unsigned int* __restrict__ vrepr16, float* __restrict__ acc)
{
    const int v = blockIdx.x * 4 + (threadIdx.x >> 6);
    const int l = threadIdx.x & 63;
    int i = offs[v];
    const int end = offs[v + 1];

    float a0 = 0.0f, a1 = 0.0f;
    for (; i + 4 <= end; i += 4) {
        const unsigned p0 = pairs[i], p1 = pairs[i + 1];
        const unsigned p2 = pairs[i + 2], p3 = pairs[i + 3];
        const unsigned r0 = vrepr16[(size_t)(p0 >> 16) * 64 + l];
        const unsigned r1 = vrepr16[(size_t)(p1 >> 16) * 64 + l];
        const unsigned r2 = vrepr16[(size_t)(p2 >> 16) * 64 + l];
        const unsigned r3 = vrepr16[(size_t)(p3 >> 16) * 64 + l];
        const float w0 = bf16_lo(p0), w1 = bf16_lo(p1);
        const float w2 = bf16_lo(p2), w3 = bf16_lo(p3);
        a0 = fmaf(bf16_lo(r0), w0, a0); a1 = fmaf(bf16_hi(r0), w0, a1);
        a0 = fmaf(bf16_lo(r1), w1, a0); a1 = fmaf(bf16_hi(r1), w1, a1);
        a0 = fmaf(bf16_lo(r2), w2, a0); a1 = fmaf(bf16_hi(r2), w2, a1);
        a0 = fmaf(bf16_lo(r3), w3, a0); a1 = fmaf(bf16_hi(r3), w3, a1);
    }
    for (; i < end; ++i) {
        const unsigned p = pairs[i];
        const unsigned r = vrepr16[(size_t)(p >> 16) * 64 + l];
        const float w = bf16_lo(p);
        a0 = fmaf(bf16_lo(r), w, a0); a1 = fmaf(bf16_hi(r), w, a1);
    }
    *reinterpret_cast<float2*>(acc + (size_t)v * OUTF + 2 * l) = make_float2(a0, a1);
}

// ---------------------------------------------------------------------------
// gemm (coalesced-weights): reads transposed weights from d_ws. 32 rows per
// block (16 KB LDS), thread = (head, row-half, column-pair); every weight
// load is lane-contiguous; each LDS b128 broadcast feeds 8 FMAs.
// ---------------------------------------------------------------------------
__global__ __launch_bounds__(256) void gemm_wt_kernel(
    const float* acc, const float* __restrict__ wT,
    const float* __restrict__ loc_b, const float* __restrict__ std_b,
    float* out)
{
    __shared__ float tile[32][OUTF];   // 16 KB
    const int t = threadIdx.x;
    const int row0 = blockIdx.x * 32;

    {
        const float4* src = reinterpret_cast<const float4*>(acc + (size_t)row0 * OUTF);
        float4* dst = reinterpret_cast<float4*>(&tile[0][0]);
#pragma unroll
        for (int j = 0; j < 4; ++j) dst[t + 256 * j] = src[t + 256 * j];
    }
    __syncthreads();

    const int h    = t >> 7;          // head (wave-uniform)
    const int half = (t >> 6) & 1;    // row half (wave-uniform)
    const int c0   = (t & 63) * 2;    // column pair
    const float* wTh = wT + h * 16384;

    float acc0[16], acc1[16];
#pragma unroll
    for (int r = 0; r < 16; ++r) { acc0[r] = 0.0f; acc1[r] = 0.0f; }

    for (int kq = 0; kq < 32; ++kq) {
        const int k = kq * 4;
        const float2 wv0 = *reinterpret_cast<const float2*>(wTh + (size_t)(k + 0) * 128 + c0);
        const float2 wv1 = *reinterpret_cast<const float2*>(wTh + (size_t)(k + 1) * 128 + c0);
        const float2 wv2 = *reinterpret_cast<const float2*>(wTh + (size_t)(k + 2) * 128 + c0);
        const float2 wv3 = *reinterpret_cast<const float2*>(wTh + (size_t)(k + 3) * 128 + c0);
#pragma unroll
        for (int r = 0; r < 16; ++r) {
            const float4 pv = *reinterpret_cast<const float4*>(&tile[half * 16 + r][k]);
            acc0[r] = fmaf(pv.x, wv0.x, acc0[r]); acc1[r] = fmaf(pv.x, wv0.y, acc1[r]);
            acc0[r] = fmaf(pv.y, wv1.x, acc0[r]); acc1[r] = fmaf(pv.y, wv1.y, acc1[r]);
            acc0[r] = fmaf(pv.z, wv2.x, acc0[r]); acc1[r] = fmaf(pv.z, wv2.y, acc1[r]);
            acc0[r] = fmaf(pv.w, wv3.x, acc0[r]); acc1[r] = fmaf(pv.w, wv3.y, acc1[r]);
        }
    }

    const float* bb = h ? std_b : loc_b;
    const float b0 = bb[c0], b1 = bb[c0 + 1];
    float* dst = out + (h ? (size_t)VNUM * OUTF : (size_t)0);
#pragma unroll
    for (int r = 0; r < 16; ++r) {
        const int row = row0 + half * 16 + r;
        if (row < VNUM) {
            float x0 = acc0[r] + b0, x1 = acc1[r] + b1;
            if (h) {
                x0 = fmaxf(x0, 0.0f) + log1pf(expf(-fabsf(x0))) + EPSF;
                x1 = fmaxf(x1, 0.0f) + log1pf(expf(-fabsf(x1))) + EPSF;
            }
            *reinterpret_cast<float2*>(dst + (size_t)row * OUTF + c0) = make_float2(x0, x1);
        }
    }
}

// Fallback gemm (no workspace): R2 version, uncoalesced weight streams.
__global__ __launch_bounds__(256) void gemm_fallback_kernel(
    const float* acc,
    const float* __restrict__ loc_w, const float* __restrict__ loc_b,
    const float* __restrict__ std_w, const float* __restrict__ std_b,
    float* out)
{
    __shared__ float tile[16][OUTF];
    const int t = threadIdx.x;
    const int row0 = blockIdx.x * 16;
    {
        const float4* src = reinterpret_cast<const float4*>(acc + (size_t)row0 * OUTF);
        float4* dst = reinterpret_cast<float4*>(&tile[0][0]);
        dst[t] = src[t]; dst[t + 256] = src[t + 256];
    }
    __syncthreads();
    const int is_std = t >> 7;
    const int c = t & 127;
    const float* w = (is_std ? std_w : loc_w) + (size_t)c * OUTF;
    const float bias = is_std ? std_b[c] : loc_b[c];
    float accv[16];
#pragma unroll
    for (int r = 0; r < 16; ++r) accv[r] = 0.0f;
    for (int k = 0; k < OUTF; k += 4) {
        const float4 wv = *reinterpret_cast<const float4*>(w + k);
#pragma unroll
        for (int r = 0; r < 16; ++r) {
            const float4 pv = *reinterpret_cast<const float4*>(&tile[r][k]);
            float a = accv[r];
            a = fmaf(pv.x, wv.x, a); a = fmaf(pv.y, wv.y, a);
            a = fmaf(pv.z, wv.z, a); a = fmaf(pv.w, wv.w, a);
            accv[r] = a;
        }
    }
    float* dst_base = out + (is_std ? (size_t)VNUM * OUTF : (size_t)0);
#pragma unroll
    for (int r = 0; r < 16; ++r) {
        const float x = accv[r] + bias;
        dst_base[(size_t)(row0 + r) * OUTF + c] =
            is_std ? (fmaxf(x, 0.0f) + log1pf(expf(-fabsf(x))) + EPSF) : x;
    }
}

extern "C" void kernel_launch(void* const* d_in, const int* in_sizes, int n_in,
                              void* d_out, int out_size, void* d_ws, size_t ws_size,
                              hipStream_t stream) {
    const int*   sidx  = (const int*)  d_in[0];
    const int*   tidx  = (const int*)  d_in[1];
    const float* enorm = (const float*)d_in[2];
    const float* esgn  = (const float*)d_in[3];
    const float* vrepr = (const float*)d_in[4];
    const float* loc_w = (const float*)d_in[5];
    const float* loc_b = (const float*)d_in[6];
    const float* std_w = (const float*)d_in[7];
    const float* std_b = (const float*)d_in[8];

    float* out = (float*)d_out;
    float* acc = out;   // loc half doubles as segment-sum buffer

    // scratch in the std half of d_out:
    //   pairs   : E uints            (1.6M)
    //   vrepr16 : VNUM*64 uints      (3.2M)
    //   cnt/offs/cursor              (~150K)   total 4.95M <= 6.4M words
    unsigned int* sbase   = (unsigned int*)(out + (size_t)VNUM * OUTF);
    unsigned int* pairs   = sbase;
    unsigned int* vrepr16 = sbase + NEDGE;
    int* cnt    = (int*)(sbase + NEDGE + (size_t)VNUM * 64);
    int* offs   = cnt + VNUM;
    int* cursor = offs + VNUM + 1;

    const bool use_ws = ws_size >= 2 * 16384 * sizeof(float);  // 128 KB for wT
    float* wT = use_ws ? (float*)d_ws : nullptr;

    hipMemsetAsync(cnt, 0, VNUM * sizeof(int), stream);

    const int prep_blocks = CONV_BLOCKS + HIST_BLOCKS + (use_ws ? 128 : 0);
    prep_kernel    <<<prep_blocks, 256, 0, stream>>>(vrepr, vrepr16, tidx, cnt,
                                                     loc_w, std_w, wT);
    scan_kernel    <<<1, 1024, 0, stream>>>(cnt, offs, cursor);
    bucket_kernel  <<<NEDGE / 256, 256, 0, stream>>>(sidx, tidx, enorm, esgn,
                                                     cursor, pairs);
    aggregate_kernel<<<VNUM / 4, 256, 0, stream>>>(offs, pairs, vrepr16, acc);

    if (use_ws) {
        gemm_wt_kernel<<<(VNUM + 31) / 32, 256, 0, stream>>>(acc, wT, loc_b, std_b, out);
    } else {
        gemm_fallback_kernel<<<VNUM / 16, 256, 0, stream>>>(acc, loc_w, loc_b,
                                                            std_w, std_b, out);
    }
}

// Round 4
// 427.027 us; speedup vs baseline: 6.7291x; 1.2264x over previous
//
#include <hip/hip_runtime.h>
#include <math.h>

#define VNUM 50000
#define OUTF 128
#define NEDGE 1600000
#define EPSF 1e-7f

#define CONV_BLOCKS 6250   // 50000*128 / (256*4)
#define HIST_BLOCKS 6250   // 1600000 / 256
#define SCAN_BLOCKS 196    // ceil(50000/256)

// ---------------------------------------------------------------------------
// bf16 helpers (self-contained, RNE)
// ---------------------------------------------------------------------------
__device__ __forceinline__ unsigned short f2bf(float f) {
    union { float f; unsigned int u; } c; c.f = f;
    unsigned int u = c.u;
    return (unsigned short)((u + 0x7FFFu + ((u >> 16) & 1u)) >> 16);
}
__device__ __forceinline__ float bf16_lo(unsigned int p) {
    union { unsigned int u; float f; } c; c.u = p << 16; return c.f;
}
__device__ __forceinline__ float bf16_hi(unsigned int p) {
    union { unsigned int u; float f; } c; c.u = p & 0xFFFF0000u; return c.f;
}

// ---------------------------------------------------------------------------
// prep: fused (a) vrepr f32 -> packed bf16x2, (b) histogram of tidx,
// (c) weight transpose into d_ws (only when ws available).
// ---------------------------------------------------------------------------
__global__ __launch_bounds__(256) void prep_kernel(
    const float* __restrict__ vrepr, unsigned int* __restrict__ vrepr16,
    const int* __restrict__ tidx, int* __restrict__ cnt,
    const float* __restrict__ loc_w, const float* __restrict__ std_w,
    float* wT)
{
    const int b = blockIdx.x, tid = threadIdx.x;
    if (b < CONV_BLOCKS) {
        const size_t base = (size_t)b * 1024 + tid * 4;
        const float4 v = *reinterpret_cast<const float4*>(vrepr + base);
        uint2 o;
        o.x = (unsigned)f2bf(v.x) | ((unsigned)f2bf(v.y) << 16);
        o.y = (unsigned)f2bf(v.z) | ((unsigned)f2bf(v.w) << 16);
        *reinterpret_cast<uint2*>(vrepr16 + base / 2) = o;
    } else if (b < CONV_BLOCKS + HIST_BLOCKS) {
        const int e = (b - CONV_BLOCKS) * 256 + tid;
        atomicAdd(&cnt[tidx[e]], 1);
    } else {
        // 128 transpose blocks: wT[h][k][c] = w_h[c][k]
        const int i = b - (CONV_BLOCKS + HIST_BLOCKS);  // 0..127
        const int h = i >> 6, kq = i & 63;
        const int k = kq * 2 + (tid >> 7);
        const int c = tid & 127;
        const float* w = h ? std_w : loc_w;
        wT[h * 16384 + k * 128 + c] = w[c * 128 + k];
    }
}

// ---------------------------------------------------------------------------
// 3-stage device-wide exclusive scan of cnt[VNUM] -> offs/cursor.
// ---------------------------------------------------------------------------
__device__ __forceinline__ int wave_incl_scan(int v, int lane) {
#pragma unroll
    for (int off = 1; off < 64; off <<= 1) {
        const int o = __shfl_up(v, off, 64);
        if (lane >= off) v += o;
    }
    return v;
}

// Stage A: per-block totals (196 blocks x 256 threads).
__global__ __launch_bounds__(256) void scan_part_kernel(
    const int* __restrict__ cnt, int* __restrict__ partials)
{
    __shared__ int wsum[4];
    const int tid = threadIdx.x;
    const int i = blockIdx.x * 256 + tid;
    int v = (i < VNUM) ? cnt[i] : 0;
    const int lane = tid & 63, wave = tid >> 6;
    // wave reduce
#pragma unroll
    for (int off = 32; off > 0; off >>= 1) v += __shfl_down(v, off, 64);
    if (lane == 0) wsum[wave] = v;
    __syncthreads();
    if (tid == 0) partials[blockIdx.x] = wsum[0] + wsum[1] + wsum[2] + wsum[3];
}

// Stage B: single tiny block scans 196 partials -> blockoff, writes offs[VNUM].
__global__ __launch_bounds__(256) void scan_mid_kernel(
    const int* __restrict__ partials, int* __restrict__ blockoff,
    int* __restrict__ offs)
{
    __shared__ int wsum[4];
    const int tid = threadIdx.x;
    int v = (tid < SCAN_BLOCKS) ? partials[tid] : 0;
    const int lane = tid & 63, wave = tid >> 6;
    int inc = wave_incl_scan(v, lane);
    if (lane == 63) wsum[wave] = inc;
    __syncthreads();
    int woff = 0;
    for (int w2 = 0; w2 < wave; ++w2) woff += wsum[w2];
    if (tid < SCAN_BLOCKS) blockoff[tid] = woff + inc - v;   // exclusive
    if (tid == 0) offs[VNUM] = wsum[0] + wsum[1] + wsum[2] + wsum[3]; // == NEDGE
}

// Stage C: final exclusive scan within each block + block offset.
__global__ __launch_bounds__(256) void scan_final_kernel(
    const int* __restrict__ cnt, const int* __restrict__ blockoff,
    int* __restrict__ offs, int* __restrict__ cursor)
{
    __shared__ int wsum[4];
    const int tid = threadIdx.x;
    const int i = blockIdx.x * 256 + tid;
    const int v = (i < VNUM) ? cnt[i] : 0;
    const int lane = tid & 63, wave = tid >> 6;
    const int inc = wave_incl_scan(v, lane);
    if (lane == 63) wsum[wave] = inc;
    __syncthreads();
    int woff = blockoff[blockIdx.x];
    for (int w2 = 0; w2 < wave; ++w2) woff += wsum[w2];
    if (i < VNUM) {
        const int e = woff + inc - v;   // exclusive prefix
        offs[i] = e; cursor[i] = e;
    }
}

// ---------------------------------------------------------------------------
// bucket: scatter packed (s<<16 | bf16(w)) into sorted position. One 4B
// write per edge.
// ---------------------------------------------------------------------------
__global__ __launch_bounds__(256) void bucket_kernel(
    const int* __restrict__ sidx, const int* __restrict__ tidx,
    const float* __restrict__ enorm, const float* __restrict__ esgn,
    int* __restrict__ cursor, unsigned int* __restrict__ pairs)
{
    const int e = blockIdx.x * 256 + threadIdx.x;
    const int t = tidx[e];
    const float w = esgn[e] * enorm[e];
    const int pos = atomicAdd(&cursor[t], 1);
    pairs[pos] = ((unsigned)sidx[e] << 16) | (unsigned)f2bf(w);
}

// ---------------------------------------------------------------------------
// aggregate: one wave per vertex, lane covers 2 columns. 256B coalesced
// bf16-row gathers, unroll-4 for MLP. Writes f32 acc (coalesced float2).
// ---------------------------------------------------------------------------
__global__ __launch_bounds__(256) void aggregate_kernel(
    const int* __restrict__ offs, const unsigned int* __restrict__ pairs,
    const unsigned int* __restrict__ vrepr16, float* __restrict__ acc)
{
    const int v = blockIdx.x * 4 + (threadIdx.x >> 6);
    const int l = threadIdx.x & 63;
    int i = offs[v];
    const int end = offs[v + 1];

    float a0 = 0.0f, a1 = 0.0f;
    for (; i + 4 <= end; i += 4) {
        const unsigned p0 = pairs[i], p1 = pairs[i + 1];
        const unsigned p2 = pairs[i + 2], p3 = pairs[i + 3];
        const unsigned r0 = vrepr16[(size_t)(p0 >> 16) * 64 + l];
        const unsigned r1 = vrepr16[(size_t)(p1 >> 16) * 64 + l];
        const unsigned r2 = vrepr16[(size_t)(p2 >> 16) * 64 + l];
        const unsigned r3 = vrepr16[(size_t)(p3 >> 16) * 64 + l];
        const float w0 = bf16_lo(p0), w1 = bf16_lo(p1);
        const float w2 = bf16_lo(p2), w3 = bf16_lo(p3);
        a0 = fmaf(bf16_lo(r0), w0, a0); a1 = fmaf(bf16_hi(r0), w0, a1);
        a0 = fmaf(bf16_lo(r1), w1, a0); a1 = fmaf(bf16_hi(r1), w1, a1);
        a0 = fmaf(bf16_lo(r2), w2, a0); a1 = fmaf(bf16_hi(r2), w2, a1);
        a0 = fmaf(bf16_lo(r3), w3, a0); a1 = fmaf(bf16_hi(r3), w3, a1);
    }
    for (; i < end; ++i) {
        const unsigned p = pairs[i];
        const unsigned r = vrepr16[(size_t)(p >> 16) * 64 + l];
        const float w = bf16_lo(p);
        a0 = fmaf(bf16_lo(r), w, a0); a1 = fmaf(bf16_hi(r), w, a1);
    }
    *reinterpret_cast<float2*>(acc + (size_t)v * OUTF + 2 * l) = make_float2(a0, a1);
}

// ---------------------------------------------------------------------------
// gemm (coalesced-weights): reads transposed weights from d_ws. 32 rows per
// block (16 KB LDS), thread = (head, row-half, column-pair).
// ---------------------------------------------------------------------------
__global__ __launch_bounds__(256) void gemm_wt_kernel(
    const float* acc, const float* __restrict__ wT,
    const float* __restrict__ loc_b, const float* __restrict__ std_b,
    float* out)
{
    __shared__ float tile[32][OUTF];   // 16 KB
    const int t = threadIdx.x;
    const int row0 = blockIdx.x * 32;

    {
        const float4* src = reinterpret_cast<const float4*>(acc + (size_t)row0 * OUTF);
        float4* dst = reinterpret_cast<float4*>(&tile[0][0]);
#pragma unroll
        for (int j = 0; j < 4; ++j) dst[t + 256 * j] = src[t + 256 * j];
    }
    __syncthreads();

    const int h    = t >> 7;          // head (wave-uniform)
    const int half = (t >> 6) & 1;    // row half (wave-uniform)
    const int c0   = (t & 63) * 2;    // column pair
    const float* wTh = wT + h * 16384;

    float acc0[16], acc1[16];
#pragma unroll
    for (int r = 0; r < 16; ++r) { acc0[r] = 0.0f; acc1[r] = 0.0f; }

    for (int kq = 0; kq < 32; ++kq) {
        const int k = kq * 4;
        const float2 wv0 = *reinterpret_cast<const float2*>(wTh + (size_t)(k + 0) * 128 + c0);
        const float2 wv1 = *reinterpret_cast<const float2*>(wTh + (size_t)(k + 1) * 128 + c0);
        const float2 wv2 = *reinterpret_cast<const float2*>(wTh + (size_t)(k + 2) * 128 + c0);
        const float2 wv3 = *reinterpret_cast<const float2*>(wTh + (size_t)(k + 3) * 128 + c0);
#pragma unroll
        for (int r = 0; r < 16; ++r) {
            const float4 pv = *reinterpret_cast<const float4*>(&tile[half * 16 + r][k]);
            acc0[r] = fmaf(pv.x, wv0.x, acc0[r]); acc1[r] = fmaf(pv.x, wv0.y, acc1[r]);
            acc0[r] = fmaf(pv.y, wv1.x, acc0[r]); acc1[r] = fmaf(pv.y, wv1.y, acc1[r]);
            acc0[r] = fmaf(pv.z, wv2.x, acc0[r]); acc1[r] = fmaf(pv.z, wv2.y, acc1[r]);
            acc0[r] = fmaf(pv.w, wv3.x, acc0[r]); acc1[r] = fmaf(pv.w, wv3.y, acc1[r]);
        }
    }

    const float* bb = h ? std_b : loc_b;
    const float b0 = bb[c0], b1 = bb[c0 + 1];
    float* dst = out + (h ? (size_t)VNUM * OUTF : (size_t)0);
#pragma unroll
    for (int r = 0; r < 16; ++r) {
        const int row = row0 + half * 16 + r;
        if (row < VNUM) {
            float x0 = acc0[r] + b0, x1 = acc1[r] + b1;
            if (h) {
                x0 = fmaxf(x0, 0.0f) + log1pf(expf(-fabsf(x0))) + EPSF;
                x1 = fmaxf(x1, 0.0f) + log1pf(expf(-fabsf(x1))) + EPSF;
            }
            *reinterpret_cast<float2*>(dst + (size_t)row * OUTF + c0) = make_float2(x0, x1);
        }
    }
}

// Fallback gemm (no workspace): uncoalesced weight streams.
__global__ __launch_bounds__(256) void gemm_fallback_kernel(
    const float* acc,
    const float* __restrict__ loc_w, const float* __restrict__ loc_b,
    const float* __restrict__ std_w, const float* __restrict__ std_b,
    float* out)
{
    __shared__ float tile[16][OUTF];
    const int t = threadIdx.x;
    const int row0 = blockIdx.x * 16;
    {
        const float4* src = reinterpret_cast<const float4*>(acc + (size_t)row0 * OUTF);
        float4* dst = reinterpret_cast<float4*>(&tile[0][0]);
        dst[t] = src[t]; dst[t + 256] = src[t + 256];
    }
    __syncthreads();
    const int is_std = t >> 7;
    const int c = t & 127;
    const float* w = (is_std ? std_w : loc_w) + (size_t)c * OUTF;
    const float bias = is_std ? std_b[c] : loc_b[c];
    float accv[16];
#pragma unroll
    for (int r = 0; r < 16; ++r) accv[r] = 0.0f;
    for (int k = 0; k < OUTF; k += 4) {
        const float4 wv = *reinterpret_cast<const float4*>(w + k);
#pragma unroll
        for (int r = 0; r < 16; ++r) {
            const float4 pv = *reinterpret_cast<const float4*>(&tile[r][k]);
            float a = accv[r];
            a = fmaf(pv.x, wv.x, a); a = fmaf(pv.y, wv.y, a);
            a = fmaf(pv.z, wv.z, a); a = fmaf(pv.w, wv.w, a);
            accv[r] = a;
        }
    }
    float* dst_base = out + (is_std ? (size_t)VNUM * OUTF : (size_t)0);
#pragma unroll
    for (int r = 0; r < 16; ++r) {
        const float x = accv[r] + bias;
        dst_base[(size_t)(row0 + r) * OUTF + c] =
            is_std ? (fmaxf(x, 0.0f) + log1pf(expf(-fabsf(x))) + EPSF) : x;
    }
}

extern "C" void kernel_launch(void* const* d_in, const int* in_sizes, int n_in,
                              void* d_out, int out_size, void* d_ws, size_t ws_size,
                              hipStream_t stream) {
    const int*   sidx  = (const int*)  d_in[0];
    const int*   tidx  = (const int*)  d_in[1];
    const float* enorm = (const float*)d_in[2];
    const float* esgn  = (const float*)d_in[3];
    const float* vrepr = (const float*)d_in[4];
    const float* loc_w = (const float*)d_in[5];
    const float* loc_b = (const float*)d_in[6];
    const float* std_w = (const float*)d_in[7];
    const float* std_b = (const float*)d_in[8];

    float* out = (float*)d_out;
    float* acc = out;   // loc half doubles as segment-sum buffer

    // scratch in the std half of d_out:
    //   pairs 1.6M | vrepr16 3.2M | cnt 50K | offs 50K+1 | cursor 50K
    //   partials 196 | blockoff 196            total ~4.95M <= 6.4M words
    unsigned int* sbase   = (unsigned int*)(out + (size_t)VNUM * OUTF);
    unsigned int* pairs   = sbase;
    unsigned int* vrepr16 = sbase + NEDGE;
    int* cnt      = (int*)(sbase + NEDGE + (size_t)VNUM * 64);
    int* offs     = cnt + VNUM;
    int* cursor   = offs + VNUM + 1;
    int* partials = cursor + VNUM;
    int* blockoff = partials + SCAN_BLOCKS;

    const bool use_ws = ws_size >= 2 * 16384 * sizeof(float);  // 128 KB for wT
    float* wT = use_ws ? (float*)d_ws : nullptr;

    hipMemsetAsync(cnt, 0, VNUM * sizeof(int), stream);

    const int prep_blocks = CONV_BLOCKS + HIST_BLOCKS + (use_ws ? 128 : 0);
    prep_kernel     <<<prep_blocks, 256, 0, stream>>>(vrepr, vrepr16, tidx, cnt,
                                                      loc_w, std_w, wT);
    scan_part_kernel <<<SCAN_BLOCKS, 256, 0, stream>>>(cnt, partials);
    scan_mid_kernel  <<<1,           256, 0, stream>>>(partials, blockoff, offs);
    scan_final_kernel<<<SCAN_BLOCKS, 256, 0, stream>>>(cnt, blockoff, offs, cursor);
    bucket_kernel   <<<NEDGE / 256, 256, 0, stream>>>(sidx, tidx, enorm, esgn,
                                                      cursor, pairs);
    aggregate_kernel<<<VNUM / 4, 256, 0, stream>>>(offs, pairs, vrepr16, acc);

    if (use_ws) {
        gemm_wt_kernel<<<(VNUM + 31) / 32, 256, 0, stream>>>(acc, wT, loc_b, std_b, out);
    } else {
        gemm_fallback_kernel<<<VNUM / 16, 256, 0, stream>>>(acc, loc_w, loc_b,
                                                            std_w, std_b, out);
    }
}